// Round 1
// baseline (363.238 us; speedup 1.0000x reference)
//
#include <hip/hip_runtime.h>
#include <hip/hip_bf16.h>

#define HWsz 16384
#define Cdim 64
#define HIDd 128
#define NEXP 4
#define NBAT 16

typedef _Float16 h8 __attribute__((ext_vector_type(8)));
typedef _Float16 h4 __attribute__((ext_vector_type(4)));
typedef float f4 __attribute__((ext_vector_type(4)));

// d_ws layout (bytes)
#define OFF_W1F 0        // 4*128*64 f16   = 65536 B
#define OFF_W2F 65536    // 4*128*128 f16  = 131072 B
#define OFF_W3F 196608   // 4*64*128 f16   = 65536 B
#define OFF_B1F 262144   // 4*128 f32      = 2048 B
#define OFF_B2F 264192   // 4*128 f32      = 2048 B
#define OFF_B3F 266240   // 4*64 f32       = 1024 B
#define OFF_GAP 267264   // 16*64 f32      = 4096 B
#define OFF_GIDX 271360  // 16*2 int       = 128 B
#define OFF_GW  271488   // 16*2 f32       = 128 B

// ---------------- BN fold + f16 cast ----------------
__global__ void fold_k(const float* __restrict__ W1, const float* __restrict__ b1,
                       const float* __restrict__ g1, const float* __restrict__ be1,
                       const float* __restrict__ m1, const float* __restrict__ v1,
                       const float* __restrict__ W2, const float* __restrict__ b2,
                       const float* __restrict__ g2, const float* __restrict__ be2,
                       const float* __restrict__ m2, const float* __restrict__ v2,
                       const float* __restrict__ W3, const float* __restrict__ b3,
                       _Float16* __restrict__ W1f, _Float16* __restrict__ W2f,
                       _Float16* __restrict__ W3f,
                       float* __restrict__ b1f, float* __restrict__ b2f,
                       float* __restrict__ b3f)
{
  const int i = blockIdx.x * 256 + threadIdx.x;
  if (i < 32768) {                       // W1 [e][o][c], eo = i/64
    const int eo = i >> 6;
    const float inv = g1[eo] * rsqrtf(v1[eo] + 1e-5f);
    W1f[i] = (_Float16)(W1[i] * inv);
  } else if (i < 98304) {                // W2 [e][o][i], eo = j/128
    const int j = i - 32768;
    const int eo = j >> 7;
    const float inv = g2[eo] * rsqrtf(v2[eo] + 1e-5f);
    W2f[j] = (_Float16)(W2[j] * inv);
  } else if (i < 131072) {               // W3 (no BN)
    const int k = i - 98304;
    W3f[k] = (_Float16)W3[k];
  } else if (i < 131584) {               // b1'
    const int l = i - 131072;
    const float inv = g1[l] * rsqrtf(v1[l] + 1e-5f);
    b1f[l] = b1[l] * inv + be1[l] - m1[l] * inv;
  } else if (i < 132096) {               // b2'
    const int l = i - 131584;
    const float inv = g2[l] * rsqrtf(v2[l] + 1e-5f);
    b2f[l] = b2[l] * inv + be2[l] - m2[l] * inv;
  } else if (i < 132352) {               // b3'
    b3f[i - 132096] = b3[i - 132096];
  }
}

// ---------------- global average pool ----------------
__global__ void gap_k(const float* __restrict__ x, float* __restrict__ gap)
{
  const int bc = blockIdx.x;             // b*64 + c, 1024 blocks
  const float* p = x + (size_t)bc * HWsz;
  const int t = threadIdx.x;             // 256
  float s = 0.f;
  for (int i = t; i < HWsz / 4; i += 256) {
    const float4 v = ((const float4*)p)[i];
    s += v.x + v.y + v.z + v.w;
  }
  for (int off = 32; off; off >>= 1) s += __shfl_down(s, off, 64);
  __shared__ float red[4];
  if ((t & 63) == 0) red[t >> 6] = s;
  __syncthreads();
  if (t == 0) gap[bc] = (red[0] + red[1] + red[2] + red[3]) * (1.0f / HWsz);
}

// ---------------- gate: softmax + top2 + aux loss ----------------
__global__ void gate_k(const float* __restrict__ gap, const float* __restrict__ gwt,
                       const float* __restrict__ gb, int* __restrict__ gidx,
                       float* __restrict__ gwo, float* __restrict__ aux)
{
  const int t = threadIdx.x;  // 64 threads, one wave
  __shared__ float logits[NBAT][NEXP];
  __shared__ float gated[NBAT][NEXP];
  {
    const int b = t >> 2, e = t & 3;
    float s = gb[e];
    for (int c = 0; c < Cdim; c++) s += gap[b * Cdim + c] * gwt[e * Cdim + c];
    logits[b][e] = s;
  }
  __syncthreads();
  if (t < NBAT) {
    const int b = t;
    float p[NEXP];
    float mx = logits[b][0];
    for (int e = 1; e < NEXP; e++) mx = fmaxf(mx, logits[b][e]);
    float sum = 0.f;
    for (int e = 0; e < NEXP; e++) { p[e] = expf(logits[b][e] - mx); sum += p[e]; }
    for (int e = 0; e < NEXP; e++) p[e] /= sum;
    int i0 = 0;
    for (int e = 1; e < NEXP; e++) if (p[e] > p[i0]) i0 = e;   // ties -> lower idx (matches lax.top_k)
    int i1 = (i0 == 0) ? 1 : 0;
    for (int e = 0; e < NEXP; e++) if (e != i0 && p[e] > p[i1]) i1 = e;
    const float s2 = p[i0] + p[i1] + 1e-8f;
    const float w0 = p[i0] / s2, w1 = p[i1] / s2;
    gidx[2 * b] = i0; gidx[2 * b + 1] = i1;
    gwo[2 * b] = w0;  gwo[2 * b + 1] = w1;
    for (int e = 0; e < NEXP; e++)
      gated[b][e] = (e == i0) ? w0 : ((e == i1) ? w1 : 0.f);
  }
  __syncthreads();
  if (t == 0) {
    float imp[NEXP] = {0.f, 0.f, 0.f, 0.f};
    for (int b = 0; b < NBAT; b++)
      for (int e = 0; e < NEXP; e++) imp[e] += gated[b][e];
    float mean = 0.f;
    for (int e = 0; e < NEXP; e++) mean += imp[e];
    mean *= 0.25f;
    float var = 0.f;
    for (int e = 0; e < NEXP; e++) { const float d = imp[e] - mean; var += d * d; }
    var *= 0.25f;
    aux[0] = var / (mean * mean + 1e-10f);
  }
}

// ---------------- fused top-2 expert MLP ----------------
// grid (256, 16): blockIdx.x = 64-wide position tile, blockIdx.y = sample b.
// 4 waves in 2x2 (mh, nh) arrangement over (out-channel, position) tiles.
__global__ __launch_bounds__(256, 2)
void moe_main_k(const float* __restrict__ x, float* __restrict__ out,
                const _Float16* __restrict__ W1f, const _Float16* __restrict__ W2f,
                const _Float16* __restrict__ W3f,
                const float* __restrict__ b1f, const float* __restrict__ b2f,
                const float* __restrict__ b3f,
                const int* __restrict__ gidx, const float* __restrict__ gwv)
{
  __shared__ __align__(16) _Float16 Xs[64][72];   // [n][c], row 144 B (16B mult)
  __shared__ __align__(16) _Float16 H1[64][136];  // [n][k], row 272 B (16B mult)
  __shared__ __align__(16) _Float16 H2[64][136];

  const int b  = blockIdx.y;
  const int n0 = blockIdx.x << 6;
  const int t  = threadIdx.x;
  const int w  = t >> 6;
  const int lane = t & 63;
  const int ln = lane & 15;   // MFMA n / m lane index
  const int q  = lane >> 4;   // quad
  const int mh = w >> 1;      // out-channel half
  const int nh = w & 1;       // position half

  // ---- stage X tile (64c x 64n) into Xs[n][c] as f16
  {
    const int c0 = t >> 4;              // 0..15
    const int n4 = (t & 15) << 2;       // 0,4,...,60
    const float* xb = x + (size_t)b * (Cdim * HWsz) + n0;
#pragma unroll
    for (int ci = 0; ci < 4; ci++) {
      const int c = c0 + (ci << 4);
      const float4 v = *(const float4*)(xb + (size_t)c * HWsz + n4);
      Xs[n4 + 0][c] = (_Float16)v.x;
      Xs[n4 + 1][c] = (_Float16)v.y;
      Xs[n4 + 2][c] = (_Float16)v.z;
      Xs[n4 + 3][c] = (_Float16)v.w;
    }
  }

  const int   ea0 = gidx[2 * b], ea1 = gidx[2 * b + 1];
  const float wa0 = gwv[2 * b],  wa1 = gwv[2 * b + 1];

  f4 oacc[2][2];
#pragma unroll
  for (int i = 0; i < 2; i++)
#pragma unroll
    for (int j = 0; j < 2; j++)
      oacc[i][j] = f4{0.f, 0.f, 0.f, 0.f};

  __syncthreads();

#pragma unroll 1
  for (int slot = 0; slot < 2; slot++) {
    const int   e  = slot ? ea1 : ea0;
    const float we = slot ? wa1 : wa0;
    const _Float16* w1 = W1f + e * (HIDd * Cdim);
    const _Float16* w2 = W2f + e * (HIDd * HIDd);
    const _Float16* w3 = W3f + e * (Cdim * HIDd);
    const float* bb1 = b1f + e * HIDd;
    const float* bb2 = b2f + e * HIDd;
    const float* bb3 = b3f + e * Cdim;

    // ---- Layer 1: H1[n][o] = relu(W1' X + b1'), K=64
#pragma unroll
    for (int ni = 0; ni < 2; ni++) {
      const int nrow = ((nh << 1) + ni) * 16 + ln;
      const h8 bf0 = *(const h8*)&Xs[nrow][q * 8];
      const h8 bf1 = *(const h8*)&Xs[nrow][32 + q * 8];
#pragma unroll
      for (int mi = 0; mi < 4; mi++) {
        const int m0 = (((mh << 2) + mi) << 4);
        const h8 a0 = *(const h8*)(w1 + (m0 + ln) * Cdim + q * 8);
        const h8 a1 = *(const h8*)(w1 + (m0 + ln) * Cdim + 32 + q * 8);
        f4 acc = {0.f, 0.f, 0.f, 0.f};
        acc = __builtin_amdgcn_mfma_f32_16x16x32_f16(a0, bf0, acc, 0, 0, 0);
        acc = __builtin_amdgcn_mfma_f32_16x16x32_f16(a1, bf1, acc, 0, 0, 0);
        const f4 bias = *(const f4*)(bb1 + m0 + q * 4);
        h4 hv;
#pragma unroll
        for (int r = 0; r < 4; r++) hv[r] = (_Float16)fmaxf(acc[r] + bias[r], 0.f);
        *(h4*)&H1[nrow][m0 + q * 4] = hv;
      }
    }
    __syncthreads();

    // ---- Layer 2: H2 = relu(W2' H1 + b2'), K=128
#pragma unroll
    for (int ni = 0; ni < 2; ni++) {
      const int nrow = ((nh << 1) + ni) * 16 + ln;
      h8 bf[4];
#pragma unroll
      for (int ks = 0; ks < 4; ks++) bf[ks] = *(const h8*)&H1[nrow][ks * 32 + q * 8];
#pragma unroll
      for (int mi = 0; mi < 4; mi++) {
        const int m0 = (((mh << 2) + mi) << 4);
        f4 acc = {0.f, 0.f, 0.f, 0.f};
#pragma unroll
        for (int ks = 0; ks < 4; ks++) {
          const h8 a = *(const h8*)(w2 + (m0 + ln) * HIDd + ks * 32 + q * 8);
          acc = __builtin_amdgcn_mfma_f32_16x16x32_f16(a, bf[ks], acc, 0, 0, 0);
        }
        const f4 bias = *(const f4*)(bb2 + m0 + q * 4);
        h4 hv;
#pragma unroll
        for (int r = 0; r < 4; r++) hv[r] = (_Float16)fmaxf(acc[r] + bias[r], 0.f);
        *(h4*)&H2[nrow][m0 + q * 4] = hv;
      }
    }
    __syncthreads();

    // ---- Layer 3: oacc += we * (W3 H2 + b3), M=64, K=128
#pragma unroll
    for (int ni = 0; ni < 2; ni++) {
      const int nrow = ((nh << 1) + ni) * 16 + ln;
      h8 bf[4];
#pragma unroll
      for (int ks = 0; ks < 4; ks++) bf[ks] = *(const h8*)&H2[nrow][ks * 32 + q * 8];
#pragma unroll
      for (int mi = 0; mi < 2; mi++) {
        const int m0 = (((mh << 1) + mi) << 4);
        f4 acc = {0.f, 0.f, 0.f, 0.f};
#pragma unroll
        for (int ks = 0; ks < 4; ks++) {
          const h8 a = *(const h8*)(w3 + (m0 + ln) * HIDd + ks * 32 + q * 8);
          acc = __builtin_amdgcn_mfma_f32_16x16x32_f16(a, bf[ks], acc, 0, 0, 0);
        }
        const f4 bias = *(const f4*)(bb3 + m0 + q * 4);
#pragma unroll
        for (int r = 0; r < 4; r++) oacc[mi][ni][r] += we * (acc[r] + bias[r]);
      }
    }
    // No extra barrier needed: next slot's first H1 write is ordered after the
    // post-L2 barrier (all H1 reads done); H2 writes after the post-L1 barrier.
  }

  // ---- store output (fp32), 16-lane-contiguous 64B segments
#pragma unroll
  for (int mi = 0; mi < 2; mi++)
#pragma unroll
    for (int ni = 0; ni < 2; ni++) {
      const int c = ((mh << 1) + mi) * 16 + q * 4;
      const int n = n0 + ((nh << 1) + ni) * 16 + ln;
#pragma unroll
      for (int r = 0; r < 4; r++)
        out[((size_t)(b * Cdim + c + r)) * HWsz + n] = oacc[mi][ni][r];
    }
}

extern "C" void kernel_launch(void* const* d_in, const int* in_sizes, int n_in,
                              void* d_out, int out_size, void* d_ws, size_t ws_size,
                              hipStream_t stream)
{
  const float* x   = (const float*)d_in[0];
  const float* W1  = (const float*)d_in[1];
  const float* b1  = (const float*)d_in[2];
  const float* g1  = (const float*)d_in[3];
  const float* be1 = (const float*)d_in[4];
  const float* m1  = (const float*)d_in[5];
  const float* v1  = (const float*)d_in[6];
  const float* W2  = (const float*)d_in[7];
  const float* b2  = (const float*)d_in[8];
  const float* g2  = (const float*)d_in[9];
  const float* be2 = (const float*)d_in[10];
  const float* m2  = (const float*)d_in[11];
  const float* v2  = (const float*)d_in[12];
  const float* W3  = (const float*)d_in[13];
  const float* b3  = (const float*)d_in[14];
  const float* gwt = (const float*)d_in[15];
  const float* gb  = (const float*)d_in[16];

  char* ws = (char*)d_ws;
  _Float16* W1f = (_Float16*)(ws + OFF_W1F);
  _Float16* W2f = (_Float16*)(ws + OFF_W2F);
  _Float16* W3f = (_Float16*)(ws + OFF_W3F);
  float* b1f = (float*)(ws + OFF_B1F);
  float* b2f = (float*)(ws + OFF_B2F);
  float* b3f = (float*)(ws + OFF_B3F);
  float* gap = (float*)(ws + OFF_GAP);
  int*   gidx = (int*)(ws + OFF_GIDX);
  float* gwo = (float*)(ws + OFF_GW);

  float* out = (float*)d_out;
  float* aux = out + (size_t)NBAT * Cdim * HWsz;  // d_out[16777216]

  hipLaunchKernelGGL(fold_k, dim3(518), dim3(256), 0, stream,
                     W1, b1, g1, be1, m1, v1, W2, b2, g2, be2, m2, v2, W3, b3,
                     W1f, W2f, W3f, b1f, b2f, b3f);
  hipLaunchKernelGGL(gap_k, dim3(NBAT * Cdim), dim3(256), 0, stream, x, gap);
  hipLaunchKernelGGL(gate_k, dim3(1), dim3(64), 0, stream, gap, gwt, gb, gidx, gwo, aux);
  hipLaunchKernelGGL(moe_main_k, dim3(HWsz / 64, NBAT), dim3(256), 0, stream,
                     x, out, W1f, W2f, W3f, b1f, b2f, b3f, gidx, gwo);
}